// Round 6
// baseline (213.206 us; speedup 1.0000x reference)
//
#include <hip/hip_runtime.h>
#include <hip/hip_bf16.h>

#define NCOL 10752   // 512*21
#define NG 15
#define NTILES 37

typedef __bf16 bf16;
typedef __attribute__((ext_vector_type(8))) __bf16 bf16x8;
typedef __attribute__((ext_vector_type(4))) __bf16 bf16x4;
typedef __attribute__((ext_vector_type(4))) float f32x4;

__constant__ int c_gsize[NG]  = {64,128,256,96,160,224,192,288,320,112,80,48,32,16,32};
__constant__ int c_gstart[NG] = {0,64,192,448,544,704,928,1120,1408,1728,1840,1920,1968,2000,2016};
// BM=64 row-tiles, sorted by descending K-iters; grid.x = colb (adjacent blocks
// stream adjacent 1KB col-segments of the same X k-rows), same-group tiles
// adjacent in y for L3 reuse of the X stripe.
__constant__ int c_tgrp[NTILES] = {8,8,8,8,8, 7,7,7,7,7, 2,2,2,2, 5,5,5,5, 6,6,6, 4,4,4, 1,1, 9,9, 3,3, 10,10, 0, 11, 12, 14, 13};
__constant__ int c_trow[NTILES] = {0,64,128,192,256, 0,64,128,192,256, 0,64,128,192, 0,64,128,192, 0,64,128, 0,64,128, 0,64, 0,64, 0,64, 0,64, 0, 0, 0, 0, 0};

struct MatPtrs { const float* p[NG]; };

constexpr int BM = 64, BN = 256, BK = 32, BKp = 40;

// 1KB-burst blocks: BN=256 so every X k-row read and every out-row write is a
// single 1KB-contiguous wave transaction. 4 waves side-by-side (64x64 each).
// X double-buffered in LDS (reg-transpose, proven swizzle); A per-wave from
// global (M is 1.7MB, L2-resident). NO launch_bounds min-waves (R4 lesson).
__global__ __launch_bounds__(256)
void matapply_kernel(const float* __restrict__ x, MatPtrs mats, float* __restrict__ out)
{
    __shared__ bf16 sB[2][BN][BKp];   // [col][k], k-chunk XOR-swizzled by (col>>3)&3

    const int tid    = threadIdx.x;
    const int colb   = blockIdx.x * BN;
    const int tileid = blockIdx.y;

    const int grp  = c_tgrp[tileid];
    const int row0 = c_trow[tileid];
    const int g    = c_gsize[grp];
    const int s    = c_gstart[grp];
    const float* __restrict__ M = mats.p[grp];

    const int wave = tid >> 6;
    const int lane = tid & 63;
    const int wc   = wave * 64;              // wave's 64-col slice
    const int lm   = lane & 15;
    const int kq   = lane >> 4;
    const int kb   = kq * 8;

    // X staging: per thread 8 rows x 4 cols. Per global-load instruction a wave
    // covers ONE row x 256 cols = 1KB contiguous.
    const int xC = (tid & 63) * 4;           // col offset 0..252
    // rows: 4*wave + 16*t + j  (t=0..1, j=0..3) -> k-consecutive quads per thread

    const int nIter = (g + BK - 1) / BK;

    f32x4 acc[4][4];
    #pragma unroll
    for (int i = 0; i < 4; i++)
        #pragma unroll
        for (int j = 0; j < 4; j++)
            acc[i][j] = (f32x4){0.f, 0.f, 0.f, 0.f};

    // A addressing: frag i -> row row0+i*16+lm, k = k0+kb..+7
    int arow[4]; bool arok[4];
    #pragma unroll
    for (int i = 0; i < 4; i++) {
        arow[i] = row0 + i * 16 + lm;
        arok[i] = arow[i] < g;
    }

    float4 a4[4][2];   // A prefetch (depth 1)
    float4 xv[8];      // X prefetch (depth 1): [t*4+j]

    auto issueA = [&](int k0) {
        #pragma unroll
        for (int i = 0; i < 4; i++) {
            a4[i][0] = make_float4(0.f, 0.f, 0.f, 0.f);
            a4[i][1] = make_float4(0.f, 0.f, 0.f, 0.f);
            if (arok[i] && (k0 + kb) < g) {
                const float* p = M + (size_t)arow[i] * g + k0 + kb;
                a4[i][0] = *(const float4*)p;
                a4[i][1] = *(const float4*)(p + 4);
            }
        }
    };
    auto issueX = [&](int k0) {
        // rows past g read the next group's data; zeroed A k-chunks null them.
        // max row index = s + nIter*32 - 1 < 2048 for all groups (checked).
        const float* p = x + (size_t)(s + k0 + 4 * wave) * NCOL + colb + xC;
        #pragma unroll
        for (int t = 0; t < 2; t++)
            #pragma unroll
            for (int j = 0; j < 4; j++)
                xv[t * 4 + j] = *(const float4*)(p + (size_t)(16 * t + j) * NCOL);
    };
    auto stageX = [&](int buf) {
        #pragma unroll
        for (int cc = 0; cc < 4; cc++) {
            const int lc = xC + cc;
            const int sw = ((lc >> 3) & 3) << 3;
            #pragma unroll
            for (int t = 0; t < 2; t++) {
                bf16x4 w;
                #pragma unroll
                for (int j = 0; j < 4; j++)
                    w[j] = (bf16)(((const float*)&xv[t * 4 + j])[cc]);
                *(bf16x4*)&sB[buf][lc][(4 * wave + 16 * t) ^ sw] = w;
            }
        }
    };

    // ---- prologue ----
    issueA(0);
    issueX(0);
    stageX(0);
    __syncthreads();

    for (int it = 0; it < nIter; ++it) {
        const int cur = it & 1;
        const bool more = (it + 1) < nIter;
        const int k0n = (it + 1) * BK;

        // convert this iter's A (loaded last iter), then re-issue
        bf16x8 af[4];
        #pragma unroll
        for (int i = 0; i < 4; i++) {
            #pragma unroll
            for (int e = 0; e < 4; e++) {
                af[i][e]     = (bf16)(((const float*)&a4[i][0])[e]);
                af[i][4 + e] = (bf16)(((const float*)&a4[i][1])[e]);
            }
        }
        if (more) issueA(k0n);
        if (more) issueX(k0n);

        // ---- compute from sB[cur] ----
        bf16x8 bfr[4];
        #pragma unroll
        for (int j = 0; j < 4; j++) {
            const int lc = wc + j * 16 + lm;
            bfr[j] = *(const bf16x8*)&sB[cur][lc][kb ^ (((lc >> 3) & 3) << 3)];
        }
        #pragma unroll
        for (int i = 0; i < 4; i++)
            #pragma unroll
            for (int j = 0; j < 4; j++)
                acc[i][j] = __builtin_amdgcn_mfma_f32_16x16x32_bf16(af[i], bfr[j], acc[i][j], 0, 0, 0);

        // ---- stage next tile, one barrier ----
        if (more) {
            stageX(1 - cur);
            __syncthreads();
        }
    }

    // ---- epilogue: C/D layout col=lane&15, row=(lane>>4)*4+reg ----
    // block writes 64 rows x 1KB contiguous
    #pragma unroll
    for (int i = 0; i < 4; i++) {
        #pragma unroll
        for (int r = 0; r < 4; r++) {
            int row = row0 + i * 16 + kq * 4 + r;
            if (row < g) {
                float* orow = out + (size_t)(s + row) * NCOL + colb + wc;
                #pragma unroll
                for (int j = 0; j < 4; j++)
                    orow[j * 16 + lm] = acc[i][j][r];
            }
        }
    }
}

extern "C" void kernel_launch(void* const* d_in, const int* in_sizes, int n_in,
                              void* d_out, int out_size, void* d_ws, size_t ws_size,
                              hipStream_t stream)
{
    const float* x = (const float*)d_in[0];
    MatPtrs mp;
    for (int i = 0; i < NG; i++) mp.p[i] = (const float*)d_in[1 + i];
    float* out = (float*)d_out;

    dim3 grid(NCOL / BN, NTILES);   // (42, 37): colb fastest
    dim3 block(256);
    matapply_kernel<<<grid, block, 0, stream>>>(x, mp, out);
}